// Round 13
// baseline (62.240 us; speedup 1.0000x reference)
//
#include <hip/hip_runtime.h>
#include <math.h>

#define EPSF 1e-12f
#define DD 768
#define LL 576

typedef unsigned short u16;
typedef __attribute__((ext_vector_type(8))) short bf16x8;
typedef __attribute__((ext_vector_type(4))) float f32x4;

__device__ __forceinline__ u16 bf16h(float v) {
  unsigned u = __float_as_uint(v);
  return (u16)((u + 0x7FFFu + ((u >> 16) & 1u)) >> 16);
}

// convert 8 floats -> packed bf16 (RNE) uint4
__device__ __forceinline__ void cvt8(const float* v, uint4& ph) {
  unsigned h[8];
#pragma unroll
  for (int i = 0; i < 8; ++i) {
    unsigned u = __float_as_uint(v[i]);
    h[i] = (u + 0x7FFFu + ((u >> 16) & 1u)) >> 16;
  }
  ph = make_uint4(h[0] | (h[1] << 16), h[2] | (h[3] << 16),
                  h[4] | (h[5] << 16), h[6] | (h[7] << 16));
}

// Layout probe: D1 = (bcast m-label) x (ones) -> 32*row ; D2 = (ones) x
// (bcast n-label) -> 32*col. True (row,col) per acc reg, any convention.
__device__ __forceinline__ void probe_layout(int lane, int* rowz, int* colz) {
  bf16x8 va, v1;
  const short ml = (short)bf16h((float)(lane & 15));
  const short on = (short)0x3F80;  // bf16(1.0)
#pragma unroll
  for (int e = 0; e < 8; ++e) { va[e] = ml; v1[e] = on; }
  f32x4 z = {0.f, 0.f, 0.f, 0.f};
  f32x4 D1 = __builtin_amdgcn_mfma_f32_16x16x32_bf16(va, v1, z, 0, 0, 0);
  f32x4 D2 = __builtin_amdgcn_mfma_f32_16x16x32_bf16(v1, va, z, 0, 0, 0);
#pragma unroll
  for (int r = 0; r < 4; ++r) {
    rowz[r] = (int)(D1[r] * 0.03125f + 0.5f);
    colz[r] = (int)(D2[r] * 0.03125f + 0.5f);
  }
}

// ---------------------------------------------------------------------------
// kW: pre-convert W into bf16 A-fragments (hi-only), fragment-major.
// ---------------------------------------------------------------------------
__global__ __launch_bounds__(256) void kW(const float* __restrict__ w,
                                          u16* __restrict__ wfH) {
  const int s = blockIdx.x;  // 0..23
  const int t = threadIdx.x;
  const int strip = t >> 6, lane = t & 63;
  const int k = strip * 16 + (lane & 15);
  const int d = s * 32 + (lane >> 4) * 8;
  float v[8];
  *(float4*)&v[0] = *(const float4*)(w + k * DD + d);
  *(float4*)&v[4] = *(const float4*)(w + k * DD + d + 4);
  uint4 ph;
  cvt8(v, ph);
  const size_t o = ((size_t)(strip * 24 + s) * 64 + lane) * 8;
  *(uint4*)(wfH + o) = ph;
}

// ---------------------------------------------------------------------------
// kA: per (n, 32-l tile): logits = W @ X, hi-only bf16. Direct transposed
// cvt-write staging (round 12). Round-13: DEPTH-2 x prefetch (32B/thread in
// flight, 2-iteration latency window) + W-fragment prefetched one step early.
// ---------------------------------------------------------------------------
__global__ __launch_bounds__(256) void kA(const float* __restrict__ x,
                                          const u16* __restrict__ wfH,
                                          u16* __restrict__ attH) {
  __shared__ __align__(16) char pool[9216];
  u16 (*Xh)[40] = (u16(*)[40])pool;            // [32l][32d swizzled]+pad
  float (*Ls)[36] = (float(*)[36])pool;        // [64k][32l+4] aliases pool
  __shared__ float red8[8][32];
  __shared__ float colinv[32], colmax[32], colscale[32];

  const int b = blockIdx.x;
  const int n = b / 18, l0 = (b % 18) * 32;
  const int t = threadIdx.x;
  const int wv = t >> 6, lane = t & 63;

  int rowz[4], colz[4];
  probe_layout(lane, rowz, colz);

  f32x4 z = {0.f, 0.f, 0.f, 0.f};
  f32x4 acc[2] = {z, z};
  float ssq4[4] = {0.f, 0.f, 0.f, 0.f};

  const int xd = t >> 3;        // 0..31 staging d (column in Xh)
  const int xl = (t & 7) * 4;   // staging l quad (rows xl..xl+3)
  const int sig = (xl >> 3) & 3;
  const int xidx = (((xd >> 3) ^ sig) << 3) + (xd & 7);  // swizzled u16 col

  const float* xbase = x + (size_t)n * DD * LL + l0;
  const u16* wfHp = wfH + ((size_t)wv * 24 * 64 + lane) * 8;

  // depth-2 x prefetch + depth-1 W-fragment prefetch
  float4 pre0 = *(const float4*)(xbase + (size_t)xd * LL + xl);         // s=0
  float4 pre1 = *(const float4*)(xbase + (size_t)(32 + xd) * LL + xl);  // s=1
  bf16x8 AhC = *(const bf16x8*)(wfHp);                                  // s=0

  for (int s = 0; s < 24; ++s) {
    __syncthreads();  // prev MFMA Xh-reads done
    {
      const float pv[4] = {pre0.x, pre0.y, pre0.z, pre0.w};
#pragma unroll
      for (int j = 0; j < 4; ++j) {
        Xh[xl + j][xidx] = bf16h(pv[j]);
        ssq4[j] = fmaf(pv[j], pv[j], ssq4[j]);
      }
    }
    pre0 = pre1;
    if (s < 22)
      pre1 = *(const float4*)(xbase + (size_t)((s + 2) * 32 + xd) * LL + xl);
    const bf16x8 Ah = AhC;
    if (s < 23) AhC = *(const bf16x8*)(wfHp + (size_t)(s + 1) * 512);
    __syncthreads();  // Xh ready
#pragma unroll
    for (int lt = 0; lt < 2; ++lt) {
      const int bl = lt * 16 + (lane & 15);
      const int pb = ((lane >> 4) ^ ((bl >> 3) & 3)) * 8;
      bf16x8 Bh = *(const bf16x8*)&Xh[bl][pb];
      acc[lt] = __builtin_amdgcn_mfma_f32_16x16x32_bf16(Ah, Bh, acc[lt], 0, 0, 0);
    }
  }

  // ssq reduce across xd-within-wave (lane bits 3,4,5); cg = lane&7
#pragma unroll
  for (int i = 0; i < 4; ++i) {
    ssq4[i] += __shfl_xor(ssq4[i], 8, 64);
    ssq4[i] += __shfl_xor(ssq4[i], 16, 64);
    ssq4[i] += __shfl_xor(ssq4[i], 32, 64);
  }
  if (lane < 8) {
#pragma unroll
    for (int i = 0; i < 4; ++i) red8[wv][lane * 4 + i] = ssq4[i];
  }
  __syncthreads();  // red8 ready; also guards Ls scatter vs last MFMA reads
  if (t < 32)
    colinv[t] =
        1.f / fmaxf(sqrtf(red8[0][t] + red8[1][t] + red8[2][t] + red8[3][t]), EPSF);
  // scatter raw logits using PROBED positions (Ls aliases dead staging pool)
#pragma unroll
  for (int lt = 0; lt < 2; ++lt)
#pragma unroll
    for (int r = 0; r < 4; ++r)
      Ls[wv * 16 + rowz[r]][lt * 16 + colz[r]] = acc[lt][r];
  __syncthreads();

  // softmax over k per column; thread (q=t>>5, cl=t&31) owns 8 k's
  const int cl = t & 31, q = t >> 5;
  const float cinv = colinv[cl];
  float sv[8];
  float m = -1e30f;
#pragma unroll
  for (int i = 0; i < 8; ++i) {
    const float vv = Ls[q * 8 + i][cl] * cinv;
    sv[i] = vv;
    m = fmaxf(m, vv);
  }
  red8[q][cl] = m;
  __syncthreads();
  if (t < 32) {
    float mm = red8[0][t];
#pragma unroll
    for (int j = 1; j < 8; ++j) mm = fmaxf(mm, red8[j][t]);
    colmax[t] = mm;
  }
  __syncthreads();
  const float M = colmax[cl];
  float ssum = 0.f;
#pragma unroll
  for (int i = 0; i < 8; ++i) {
    const float e = __expf(sv[i] - M);
    sv[i] = e;
    ssum += e;
  }
  red8[q][cl] = ssum;
  __syncthreads();
  if (t < 32) {
    float ss = red8[0][t];
#pragma unroll
    for (int j = 1; j < 8; ++j) ss += red8[j][t];
    colscale[t] = colinv[t] / ss;
  }
  __syncthreads();
  const float cs = colscale[cl];
  u16* aH = attH + (size_t)n * 64 * LL + l0 + cl;
#pragma unroll
  for (int i = 0; i < 8; ++i) {
    const int k = q * 8 + i;
    aH[(size_t)k * LL] = bf16h(sv[i] * cs);
  }
}

// ---------------------------------------------------------------------------
// kB: per (n, 64-d tile): out[k][d] = sum_l att'[k][l] * x[d][l].
// Hi-only bf16 MFMA. Reg-prefetched staging. Probe-based output positions.
// Fused per-(k, d-tile) sumsq partials -> part[b][k] (deterministic).
// ---------------------------------------------------------------------------
__global__ __launch_bounds__(256) void kB(const float* __restrict__ x,
                                          const u16* __restrict__ attH,
                                          float* __restrict__ out,
                                          float* __restrict__ part) {
  __shared__ __align__(16) u16 AH[64][40];
  __shared__ __align__(16) u16 Xh[64][40];
  const int b = blockIdx.x;
  const int n = b / 12, d0 = (b % 12) * 64;
  const int t = threadIdx.x;
  const int wv = t >> 6, lane = t & 63;

  int rowz[4], colz[4];
  probe_layout(lane, rowz, colz);

  f32x4 z = {0.f, 0.f, 0.f, 0.f};
  f32x4 acc[4] = {z, z, z, z};

  const int rk = t >> 2;       // staging row 0..63
  const int lb = (t & 3) * 8;  // l offset 0,8,16,24

  const u16* aHb = attH + ((size_t)n * 64 + rk) * LL + lb;
  const float* xb = x + ((size_t)n * DD + d0 + rk) * LL + lb;

  uint4 pAH = *(const uint4*)aHb;
  float4 pX0 = *(const float4*)xb;
  float4 pX1 = *(const float4*)(xb + 4);

  for (int s = 0; s < 18; ++s) {
    __syncthreads();  // prev MFMA reads done
    *(uint4*)&AH[rk][lb] = pAH;
    {
      float v[8] = {pX0.x, pX0.y, pX0.z, pX0.w, pX1.x, pX1.y, pX1.z, pX1.w};
      uint4 ph;
      cvt8(v, ph);
      *(uint4*)&Xh[rk][lb] = ph;
    }
    if (s < 17) {
      const int lo = (s + 1) * 32;
      pAH = *(const uint4*)(aHb + lo);
      pX0 = *(const float4*)(xb + lo);
      pX1 = *(const float4*)(xb + lo + 4);
    }
    __syncthreads();  // staged
    const int ar = wv * 16 + (lane & 15);
    const int ab = (lane >> 4) * 8;
    bf16x8 Ah = *(const bf16x8*)&AH[ar][ab];
#pragma unroll
    for (int dt = 0; dt < 4; ++dt) {
      const int br = dt * 16 + (lane & 15);
      bf16x8 Bh = *(const bf16x8*)&Xh[br][ab];
      acc[dt] = __builtin_amdgcn_mfma_f32_16x16x32_bf16(Ah, Bh, acc[dt], 0, 0, 0);
    }
  }

  // store raw out using PROBED positions
  float* ob = out + ((size_t)n * 64 + wv * 16) * DD + d0;
#pragma unroll
  for (int dt = 0; dt < 4; ++dt)
#pragma unroll
    for (int r = 0; r < 4; ++r)
      ob[(size_t)rowz[r] * DD + dt * 16 + colz[r]] = acc[dt][r];

  // fused per-(k, d-tile) sumsq partial (deterministic, no atomics)
#pragma unroll
  for (int r = 0; r < 4; ++r) {
    float s = 0.f;
#pragma unroll
    for (int dt = 0; dt < 4; ++dt) s = fmaf(acc[dt][r], acc[dt][r], s);
    s += __shfl_xor(s, 1, 64);
    s += __shfl_xor(s, 2, 64);
    s += __shfl_xor(s, 4, 64);
    s += __shfl_xor(s, 8, 64);
    if ((lane & 15) == 0)
      part[(size_t)b * 64 + wv * 16 + rowz[r]] = s;
  }
}

// ---------------------------------------------------------------------------
// kC3f: one block per (n,k) row. Lanes 0-11 read the 12 d-tile partials,
// shuffle-reduce, broadcast; scale row in place. ginv = 1/8 folded.
// ---------------------------------------------------------------------------
__global__ __launch_bounds__(64) void kC3f(const float* __restrict__ part,
                                           float* __restrict__ out) {
  const int row = blockIdx.x;  // n*64 + k
  const int n = row >> 6, k = row & 63;
  const int t = threadIdx.x;
  float p = (t < 12) ? part[(size_t)(n * 12 + t) * 64 + k] : 0.f;
  p += __shfl_xor(p, 1, 64);
  p += __shfl_xor(p, 2, 64);
  p += __shfl_xor(p, 4, 64);
  p += __shfl_xor(p, 8, 64);
  const float ss = __shfl(p, 0, 64);
  const float sc = 0.125f / fmaxf(sqrtf(ss), EPSF);
  float4* o = (float4*)(out + (size_t)row * DD);
#pragma unroll
  for (int j = 0; j < 3; ++j) {
    float4 v = o[t + 64 * j];
    v.x *= sc; v.y *= sc; v.z *= sc; v.w *= sc;
    o[t + 64 * j] = v;
  }
}

// ---------------------------------------------------------------------------
extern "C" void kernel_launch(void* const* d_in, const int* in_sizes, int n_in,
                              void* d_out, int out_size, void* d_ws, size_t ws_size,
                              hipStream_t stream) {
  const float* x = (const float*)d_in[0];  // [64,768,24,24]
  const float* w = (const float*)d_in[1];  // [64,768]
  float* out = (float*)d_out;              // [64, 64*768]

  u16* attH = (u16*)d_ws;                    // [64,64,576] bf16 hi only
  u16* wfH = attH + (size_t)2359296;         // W fragments hi [4*24*64*8]
  float* part = (float*)(wfH + 49152);       // [768][64] sumsq partials

  kW<<<24, 256, 0, stream>>>(w, wfH);
  kA<<<1152, 256, 0, stream>>>(x, wfH, attH);
  kB<<<768, 256, 0, stream>>>(x, attH, out, part);
  kC3f<<<4096, 64, 0, stream>>>(part, out);
}

// Round 14
// 61.354 us; speedup vs baseline: 1.0144x; 1.0144x over previous
//
#include <hip/hip_runtime.h>
#include <math.h>

#define EPSF 1e-12f
#define DD 768
#define LL 576

typedef unsigned short u16;
typedef __attribute__((ext_vector_type(8))) short bf16x8;
typedef __attribute__((ext_vector_type(4))) float f32x4;

__device__ __forceinline__ u16 bf16h(float v) {
  unsigned u = __float_as_uint(v);
  return (u16)((u + 0x7FFFu + ((u >> 16) & 1u)) >> 16);
}

// convert 8 floats -> packed bf16 (RNE) uint4
__device__ __forceinline__ void cvt8(const float* v, uint4& ph) {
  unsigned h[8];
#pragma unroll
  for (int i = 0; i < 8; ++i) {
    unsigned u = __float_as_uint(v[i]);
    h[i] = (u + 0x7FFFu + ((u >> 16) & 1u)) >> 16;
  }
  ph = make_uint4(h[0] | (h[1] << 16), h[2] | (h[3] << 16),
                  h[4] | (h[5] << 16), h[6] | (h[7] << 16));
}

// Layout probe: D1 = (bcast m-label) x (ones) -> 32*row ; D2 = (ones) x
// (bcast n-label) -> 32*col. True (row,col) per acc reg, any convention.
__device__ __forceinline__ void probe_layout(int lane, int* rowz, int* colz) {
  bf16x8 va, v1;
  const short ml = (short)bf16h((float)(lane & 15));
  const short on = (short)0x3F80;  // bf16(1.0)
#pragma unroll
  for (int e = 0; e < 8; ++e) { va[e] = ml; v1[e] = on; }
  f32x4 z = {0.f, 0.f, 0.f, 0.f};
  f32x4 D1 = __builtin_amdgcn_mfma_f32_16x16x32_bf16(va, v1, z, 0, 0, 0);
  f32x4 D2 = __builtin_amdgcn_mfma_f32_16x16x32_bf16(v1, va, z, 0, 0, 0);
#pragma unroll
  for (int r = 0; r < 4; ++r) {
    rowz[r] = (int)(D1[r] * 0.03125f + 0.5f);
    colz[r] = (int)(D2[r] * 0.03125f + 0.5f);
  }
}

// ---------------------------------------------------------------------------
// kW: pre-convert W into bf16 A-fragments (hi-only), fragment-major.
// ---------------------------------------------------------------------------
__global__ __launch_bounds__(256) void kW(const float* __restrict__ w,
                                          u16* __restrict__ wfH) {
  const int s = blockIdx.x;  // 0..23
  const int t = threadIdx.x;
  const int strip = t >> 6, lane = t & 63;
  const int k = strip * 16 + (lane & 15);
  const int d = s * 32 + (lane >> 4) * 8;
  float v[8];
  *(float4*)&v[0] = *(const float4*)(w + k * DD + d);
  *(float4*)&v[4] = *(const float4*)(w + k * DD + d + 4);
  uint4 ph;
  cvt8(v, ph);
  const size_t o = ((size_t)(strip * 24 + s) * 64 + lane) * 8;
  *(uint4*)(wfH + o) = ph;
}

// ---------------------------------------------------------------------------
// kA: per (n, 32-l tile): logits = W @ X, hi-only bf16. Direct transposed
// cvt-write staging (round 12). Round-14: DOUBLE-BUFFERED Xh, ONE barrier
// per step. Parity safety: a wave re-writes buf p at iter s+2 only after
// sync(s+1); every wave reaches sync(s+1) only after its MFMA(s) reads of
// buf p -> one full barrier separates writes from conflicting reads.
// ---------------------------------------------------------------------------
__global__ __launch_bounds__(256) void kA(const float* __restrict__ x,
                                          const u16* __restrict__ wfH,
                                          u16* __restrict__ attH) {
  __shared__ __align__(16) char pool[9216];
  u16 (*Xh)[32][40] = (u16(*)[32][40])pool;    // [2][32l][32d swz]+pad, 5120B
  float (*Ls)[36] = (float(*)[36])pool;        // [64k][32l+4] aliases pool
  __shared__ float red8[8][32];
  __shared__ float colinv[32], colmax[32], colscale[32];

  const int b = blockIdx.x;
  const int n = b / 18, l0 = (b % 18) * 32;
  const int t = threadIdx.x;
  const int wv = t >> 6, lane = t & 63;

  int rowz[4], colz[4];
  probe_layout(lane, rowz, colz);

  f32x4 z = {0.f, 0.f, 0.f, 0.f};
  f32x4 acc[2] = {z, z};
  float ssq4[4] = {0.f, 0.f, 0.f, 0.f};

  const int xd = t >> 3;        // 0..31 staging d (column in Xh)
  const int xl = (t & 7) * 4;   // staging l quad (rows xl..xl+3)
  const int sig = (xl >> 3) & 3;
  const int xidx = (((xd >> 3) ^ sig) << 3) + (xd & 7);  // swizzled u16 col

  const float* xbase = x + (size_t)n * DD * LL + l0;
  const u16* wfHp = wfH + ((size_t)wv * 24 * 64 + lane) * 8;

  float4 pre = *(const float4*)(xbase + (size_t)xd * LL + xl);
  bf16x8 AhC = *(const bf16x8*)(wfHp);  // fragment for s=0

  for (int s = 0; s < 24; ++s) {
    // write phase into buf s&1 (reads of this buf from iter s-2 are
    // separated by sync(s-1))
    {
      const float pv[4] = {pre.x, pre.y, pre.z, pre.w};
#pragma unroll
      for (int j = 0; j < 4; ++j) {
        Xh[s & 1][xl + j][xidx] = bf16h(pv[j]);
        ssq4[j] = fmaf(pv[j], pv[j], ssq4[j]);
      }
    }
    if (s < 23)
      pre = *(const float4*)(xbase + (size_t)((s + 1) * 32 + xd) * LL + xl);
    const bf16x8 Ah = AhC;
    if (s < 23) AhC = *(const bf16x8*)(wfHp + (size_t)(s + 1) * 512);
    __syncthreads();  // buf s&1 ready for all waves
#pragma unroll
    for (int lt = 0; lt < 2; ++lt) {
      const int bl = lt * 16 + (lane & 15);
      const int pb = ((lane >> 4) ^ ((bl >> 3) & 3)) * 8;
      bf16x8 Bh = *(const bf16x8*)&Xh[s & 1][bl][pb];
      acc[lt] = __builtin_amdgcn_mfma_f32_16x16x32_bf16(Ah, Bh, acc[lt], 0, 0, 0);
    }
  }

  // ssq reduce across xd-within-wave (lane bits 3,4,5); cg = lane&7
#pragma unroll
  for (int i = 0; i < 4; ++i) {
    ssq4[i] += __shfl_xor(ssq4[i], 8, 64);
    ssq4[i] += __shfl_xor(ssq4[i], 16, 64);
    ssq4[i] += __shfl_xor(ssq4[i], 32, 64);
  }
  if (lane < 8) {
#pragma unroll
    for (int i = 0; i < 4; ++i) red8[wv][lane * 4 + i] = ssq4[i];
  }
  __syncthreads();  // red8 ready; guards Ls scatter vs last MFMA reads
  if (t < 32)
    colinv[t] =
        1.f / fmaxf(sqrtf(red8[0][t] + red8[1][t] + red8[2][t] + red8[3][t]), EPSF);
  // scatter raw logits using PROBED positions (Ls aliases dead staging pool)
#pragma unroll
  for (int lt = 0; lt < 2; ++lt)
#pragma unroll
    for (int r = 0; r < 4; ++r)
      Ls[wv * 16 + rowz[r]][lt * 16 + colz[r]] = acc[lt][r];
  __syncthreads();

  // softmax over k per column; thread (q=t>>5, cl=t&31) owns 8 k's
  const int cl = t & 31, q = t >> 5;
  const float cinv = colinv[cl];
  float sv[8];
  float m = -1e30f;
#pragma unroll
  for (int i = 0; i < 8; ++i) {
    const float vv = Ls[q * 8 + i][cl] * cinv;
    sv[i] = vv;
    m = fmaxf(m, vv);
  }
  red8[q][cl] = m;
  __syncthreads();
  if (t < 32) {
    float mm = red8[0][t];
#pragma unroll
    for (int j = 1; j < 8; ++j) mm = fmaxf(mm, red8[j][t]);
    colmax[t] = mm;
  }
  __syncthreads();
  const float M = colmax[cl];
  float ssum = 0.f;
#pragma unroll
  for (int i = 0; i < 8; ++i) {
    const float e = __expf(sv[i] - M);
    sv[i] = e;
    ssum += e;
  }
  red8[q][cl] = ssum;
  __syncthreads();
  if (t < 32) {
    float ss = red8[0][t];
#pragma unroll
    for (int j = 1; j < 8; ++j) ss += red8[j][t];
    colscale[t] = colinv[t] / ss;
  }
  __syncthreads();
  const float cs = colscale[cl];
  u16* aH = attH + (size_t)n * 64 * LL + l0 + cl;
#pragma unroll
  for (int i = 0; i < 8; ++i) {
    const int k = q * 8 + i;
    aH[(size_t)k * LL] = bf16h(sv[i] * cs);
  }
}

// ---------------------------------------------------------------------------
// kB: per (n, 64-d tile): out[k][d] = sum_l att'[k][l] * x[d][l].
// Hi-only bf16 MFMA. Reg-prefetched staging. Probe-based output positions.
// Fused per-(k, d-tile) sumsq partials -> part[b][k] (deterministic).
// ---------------------------------------------------------------------------
__global__ __launch_bounds__(256) void kB(const float* __restrict__ x,
                                          const u16* __restrict__ attH,
                                          float* __restrict__ out,
                                          float* __restrict__ part) {
  __shared__ __align__(16) u16 AH[64][40];
  __shared__ __align__(16) u16 Xh[64][40];
  const int b = blockIdx.x;
  const int n = b / 12, d0 = (b % 12) * 64;
  const int t = threadIdx.x;
  const int wv = t >> 6, lane = t & 63;

  int rowz[4], colz[4];
  probe_layout(lane, rowz, colz);

  f32x4 z = {0.f, 0.f, 0.f, 0.f};
  f32x4 acc[4] = {z, z, z, z};

  const int rk = t >> 2;       // staging row 0..63
  const int lb = (t & 3) * 8;  // l offset 0,8,16,24

  const u16* aHb = attH + ((size_t)n * 64 + rk) * LL + lb;
  const float* xb = x + ((size_t)n * DD + d0 + rk) * LL + lb;

  uint4 pAH = *(const uint4*)aHb;
  float4 pX0 = *(const float4*)xb;
  float4 pX1 = *(const float4*)(xb + 4);

  for (int s = 0; s < 18; ++s) {
    __syncthreads();  // prev MFMA reads done
    *(uint4*)&AH[rk][lb] = pAH;
    {
      float v[8] = {pX0.x, pX0.y, pX0.z, pX0.w, pX1.x, pX1.y, pX1.z, pX1.w};
      uint4 ph;
      cvt8(v, ph);
      *(uint4*)&Xh[rk][lb] = ph;
    }
    if (s < 17) {
      const int lo = (s + 1) * 32;
      pAH = *(const uint4*)(aHb + lo);
      pX0 = *(const float4*)(xb + lo);
      pX1 = *(const float4*)(xb + lo + 4);
    }
    __syncthreads();  // staged
    const int ar = wv * 16 + (lane & 15);
    const int ab = (lane >> 4) * 8;
    bf16x8 Ah = *(const bf16x8*)&AH[ar][ab];
#pragma unroll
    for (int dt = 0; dt < 4; ++dt) {
      const int br = dt * 16 + (lane & 15);
      bf16x8 Bh = *(const bf16x8*)&Xh[br][ab];
      acc[dt] = __builtin_amdgcn_mfma_f32_16x16x32_bf16(Ah, Bh, acc[dt], 0, 0, 0);
    }
  }

  // store raw out using PROBED positions
  float* ob = out + ((size_t)n * 64 + wv * 16) * DD + d0;
#pragma unroll
  for (int dt = 0; dt < 4; ++dt)
#pragma unroll
    for (int r = 0; r < 4; ++r)
      ob[(size_t)rowz[r] * DD + dt * 16 + colz[r]] = acc[dt][r];

  // fused per-(k, d-tile) sumsq partial (deterministic, no atomics)
#pragma unroll
  for (int r = 0; r < 4; ++r) {
    float s = 0.f;
#pragma unroll
    for (int dt = 0; dt < 4; ++dt) s = fmaf(acc[dt][r], acc[dt][r], s);
    s += __shfl_xor(s, 1, 64);
    s += __shfl_xor(s, 2, 64);
    s += __shfl_xor(s, 4, 64);
    s += __shfl_xor(s, 8, 64);
    if ((lane & 15) == 0)
      part[(size_t)b * 64 + wv * 16 + rowz[r]] = s;
  }
}

// ---------------------------------------------------------------------------
// kC3f: one block per (n,k) row. Lanes 0-11 read the 12 d-tile partials,
// shuffle-reduce, broadcast; scale row in place. ginv = 1/8 folded.
// ---------------------------------------------------------------------------
__global__ __launch_bounds__(64) void kC3f(const float* __restrict__ part,
                                           float* __restrict__ out) {
  const int row = blockIdx.x;  // n*64 + k
  const int n = row >> 6, k = row & 63;
  const int t = threadIdx.x;
  float p = (t < 12) ? part[(size_t)(n * 12 + t) * 64 + k] : 0.f;
  p += __shfl_xor(p, 1, 64);
  p += __shfl_xor(p, 2, 64);
  p += __shfl_xor(p, 4, 64);
  p += __shfl_xor(p, 8, 64);
  const float ss = __shfl(p, 0, 64);
  const float sc = 0.125f / fmaxf(sqrtf(ss), EPSF);
  float4* o = (float4*)(out + (size_t)row * DD);
#pragma unroll
  for (int j = 0; j < 3; ++j) {
    float4 v = o[t + 64 * j];
    v.x *= sc; v.y *= sc; v.z *= sc; v.w *= sc;
    o[t + 64 * j] = v;
  }
}

// ---------------------------------------------------------------------------
extern "C" void kernel_launch(void* const* d_in, const int* in_sizes, int n_in,
                              void* d_out, int out_size, void* d_ws, size_t ws_size,
                              hipStream_t stream) {
  const float* x = (const float*)d_in[0];  // [64,768,24,24]
  const float* w = (const float*)d_in[1];  // [64,768]
  float* out = (float*)d_out;              // [64, 64*768]

  u16* attH = (u16*)d_ws;                    // [64,64,576] bf16 hi only
  u16* wfH = attH + (size_t)2359296;         // W fragments hi [4*24*64*8]
  float* part = (float*)(wfH + 49152);       // [768][64] sumsq partials

  kW<<<24, 256, 0, stream>>>(w, wfH);
  kA<<<1152, 256, 0, stream>>>(x, wfH, attH);
  kB<<<768, 256, 0, stream>>>(x, attH, out, part);
  kC3f<<<4096, 64, 0, stream>>>(part, out);
}

// Round 15
// 58.888 us; speedup vs baseline: 1.0569x; 1.0419x over previous
//
#include <hip/hip_runtime.h>
#include <math.h>

#define EPSF 1e-12f
#define DD 768
#define LL 576

typedef unsigned short u16;
typedef __attribute__((ext_vector_type(8))) short bf16x8;
typedef __attribute__((ext_vector_type(4))) float f32x4;

__device__ __forceinline__ u16 bf16h(float v) {
  unsigned u = __float_as_uint(v);
  return (u16)((u + 0x7FFFu + ((u >> 16) & 1u)) >> 16);
}

// convert 8 floats -> packed bf16 (RNE) uint4
__device__ __forceinline__ void cvt8(const float* v, uint4& ph) {
  unsigned h[8];
#pragma unroll
  for (int i = 0; i < 8; ++i) {
    unsigned u = __float_as_uint(v[i]);
    h[i] = (u + 0x7FFFu + ((u >> 16) & 1u)) >> 16;
  }
  ph = make_uint4(h[0] | (h[1] << 16), h[2] | (h[3] << 16),
                  h[4] | (h[5] << 16), h[6] | (h[7] << 16));
}

// Layout probe: D1 = (bcast m-label) x (ones) -> 32*row ; D2 = (ones) x
// (bcast n-label) -> 32*col. True (row,col) per acc reg, any convention.
__device__ __forceinline__ void probe_layout(int lane, int* rowz, int* colz) {
  bf16x8 va, v1;
  const short ml = (short)bf16h((float)(lane & 15));
  const short on = (short)0x3F80;  // bf16(1.0)
#pragma unroll
  for (int e = 0; e < 8; ++e) { va[e] = ml; v1[e] = on; }
  f32x4 z = {0.f, 0.f, 0.f, 0.f};
  f32x4 D1 = __builtin_amdgcn_mfma_f32_16x16x32_bf16(va, v1, z, 0, 0, 0);
  f32x4 D2 = __builtin_amdgcn_mfma_f32_16x16x32_bf16(v1, va, z, 0, 0, 0);
#pragma unroll
  for (int r = 0; r < 4; ++r) {
    rowz[r] = (int)(D1[r] * 0.03125f + 0.5f);
    colz[r] = (int)(D2[r] * 0.03125f + 0.5f);
  }
}

// ---------------------------------------------------------------------------
// kW: pre-convert W into bf16 A-fragments (hi-only), fragment-major.
// ---------------------------------------------------------------------------
__global__ __launch_bounds__(256) void kW(const float* __restrict__ w,
                                          u16* __restrict__ wfH) {
  const int s = blockIdx.x;  // 0..23
  const int t = threadIdx.x;
  const int strip = t >> 6, lane = t & 63;
  const int k = strip * 16 + (lane & 15);
  const int d = s * 32 + (lane >> 4) * 8;
  float v[8];
  *(float4*)&v[0] = *(const float4*)(w + k * DD + d);
  *(float4*)&v[4] = *(const float4*)(w + k * DD + d + 4);
  uint4 ph;
  cvt8(v, ph);
  const size_t o = ((size_t)(strip * 24 + s) * 64 + lane) * 8;
  *(uint4*)(wfH + o) = ph;
}

// ---------------------------------------------------------------------------
// kA: per (n, 32-l tile): logits = W @ X, hi-only bf16.
// Direct transposed cvt-write from staging registers (round-12 verified
// structure, best known). 2 barriers/step. Write conflicts: per wave, cols =
// one 8-slot; sigma(row)=(row>>3)&3 gives each of the 4 rows per bank-class
// a distinct dword-quad -> 32 banks, 2 lanes/dword (free).
// ---------------------------------------------------------------------------
__global__ __launch_bounds__(256) void kA(const float* __restrict__ x,
                                          const u16* __restrict__ wfH,
                                          u16* __restrict__ attH) {
  __shared__ __align__(16) char pool[9216];
  u16 (*Xh)[40] = (u16(*)[40])pool;            // [32l][32d swizzled]+pad
  float (*Ls)[36] = (float(*)[36])pool;        // [64k][32l+4] aliases pool
  __shared__ float red8[8][32];
  __shared__ float colinv[32], colmax[32], colscale[32];

  const int b = blockIdx.x;
  const int n = b / 18, l0 = (b % 18) * 32;
  const int t = threadIdx.x;
  const int wv = t >> 6, lane = t & 63;

  int rowz[4], colz[4];
  probe_layout(lane, rowz, colz);

  f32x4 z = {0.f, 0.f, 0.f, 0.f};
  f32x4 acc[2] = {z, z};
  float ssq4[4] = {0.f, 0.f, 0.f, 0.f};

  const int xd = t >> 3;        // 0..31 staging d (column in Xh)
  const int xl = (t & 7) * 4;   // staging l quad (rows xl..xl+3)
  const int sig = (xl >> 3) & 3;
  const int xidx = (((xd >> 3) ^ sig) << 3) + (xd & 7);  // swizzled u16 col

  const float* xbase = x + (size_t)n * DD * LL + l0;
  const u16* wfHp = wfH + ((size_t)wv * 24 * 64 + lane) * 8;

  float4 pre = *(const float4*)(xbase + (size_t)xd * LL + xl);

  for (int s = 0; s < 24; ++s) {
    __syncthreads();  // prev MFMA Xh-reads done
    {
      const float pv[4] = {pre.x, pre.y, pre.z, pre.w};
#pragma unroll
      for (int j = 0; j < 4; ++j) {
        Xh[xl + j][xidx] = bf16h(pv[j]);
        ssq4[j] = fmaf(pv[j], pv[j], ssq4[j]);
      }
    }
    if (s < 23)
      pre = *(const float4*)(xbase + (size_t)((s + 1) * 32 + xd) * LL + xl);
    bf16x8 Ah = *(const bf16x8*)(wfHp + (size_t)s * 512);
    __syncthreads();  // Xh ready
#pragma unroll
    for (int lt = 0; lt < 2; ++lt) {
      const int bl = lt * 16 + (lane & 15);
      const int pb = ((lane >> 4) ^ ((bl >> 3) & 3)) * 8;
      bf16x8 Bh = *(const bf16x8*)&Xh[bl][pb];
      acc[lt] = __builtin_amdgcn_mfma_f32_16x16x32_bf16(Ah, Bh, acc[lt], 0, 0, 0);
    }
  }

  // ssq reduce across xd-within-wave (lane bits 3,4,5); cg = lane&7
#pragma unroll
  for (int i = 0; i < 4; ++i) {
    ssq4[i] += __shfl_xor(ssq4[i], 8, 64);
    ssq4[i] += __shfl_xor(ssq4[i], 16, 64);
    ssq4[i] += __shfl_xor(ssq4[i], 32, 64);
  }
  if (lane < 8) {
#pragma unroll
    for (int i = 0; i < 4; ++i) red8[wv][lane * 4 + i] = ssq4[i];
  }
  __syncthreads();  // red8 ready; also guards Ls scatter vs last MFMA reads
  if (t < 32)
    colinv[t] =
        1.f / fmaxf(sqrtf(red8[0][t] + red8[1][t] + red8[2][t] + red8[3][t]), EPSF);
  // scatter raw logits using PROBED positions (Ls aliases dead staging pool)
#pragma unroll
  for (int lt = 0; lt < 2; ++lt)
#pragma unroll
    for (int r = 0; r < 4; ++r)
      Ls[wv * 16 + rowz[r]][lt * 16 + colz[r]] = acc[lt][r];
  __syncthreads();

  // softmax over k per column; thread (q=t>>5, cl=t&31) owns 8 k's
  const int cl = t & 31, q = t >> 5;
  const float cinv = colinv[cl];
  float sv[8];
  float m = -1e30f;
#pragma unroll
  for (int i = 0; i < 8; ++i) {
    const float vv = Ls[q * 8 + i][cl] * cinv;
    sv[i] = vv;
    m = fmaxf(m, vv);
  }
  red8[q][cl] = m;
  __syncthreads();
  if (t < 32) {
    float mm = red8[0][t];
#pragma unroll
    for (int j = 1; j < 8; ++j) mm = fmaxf(mm, red8[j][t]);
    colmax[t] = mm;
  }
  __syncthreads();
  const float M = colmax[cl];
  float ssum = 0.f;
#pragma unroll
  for (int i = 0; i < 8; ++i) {
    const float e = __expf(sv[i] - M);
    sv[i] = e;
    ssum += e;
  }
  red8[q][cl] = ssum;
  __syncthreads();
  if (t < 32) {
    float ss = red8[0][t];
#pragma unroll
    for (int j = 1; j < 8; ++j) ss += red8[j][t];
    colscale[t] = colinv[t] / ss;
  }
  __syncthreads();
  const float cs = colscale[cl];
  u16* aH = attH + (size_t)n * 64 * LL + l0 + cl;
#pragma unroll
  for (int i = 0; i < 8; ++i) {
    const int k = q * 8 + i;
    aH[(size_t)k * LL] = bf16h(sv[i] * cs);
  }
}

// ---------------------------------------------------------------------------
// kB: per (n, 64-d tile): out[k][d] = sum_l att'[k][l] * x[d][l].
// Hi-only bf16 MFMA. Reg-prefetched staging. Probe-based output positions.
// Fused per-(k, d-tile) sumsq partials -> part[b][k] (deterministic).
// ---------------------------------------------------------------------------
__global__ __launch_bounds__(256) void kB(const float* __restrict__ x,
                                          const u16* __restrict__ attH,
                                          float* __restrict__ out,
                                          float* __restrict__ part) {
  __shared__ __align__(16) u16 AH[64][40];
  __shared__ __align__(16) u16 Xh[64][40];
  const int b = blockIdx.x;
  const int n = b / 12, d0 = (b % 12) * 64;
  const int t = threadIdx.x;
  const int wv = t >> 6, lane = t & 63;

  int rowz[4], colz[4];
  probe_layout(lane, rowz, colz);

  f32x4 z = {0.f, 0.f, 0.f, 0.f};
  f32x4 acc[4] = {z, z, z, z};

  const int rk = t >> 2;       // staging row 0..63
  const int lb = (t & 3) * 8;  // l offset 0,8,16,24

  const u16* aHb = attH + ((size_t)n * 64 + rk) * LL + lb;
  const float* xb = x + ((size_t)n * DD + d0 + rk) * LL + lb;

  uint4 pAH = *(const uint4*)aHb;
  float4 pX0 = *(const float4*)xb;
  float4 pX1 = *(const float4*)(xb + 4);

  for (int s = 0; s < 18; ++s) {
    __syncthreads();  // prev MFMA reads done
    *(uint4*)&AH[rk][lb] = pAH;
    {
      float v[8] = {pX0.x, pX0.y, pX0.z, pX0.w, pX1.x, pX1.y, pX1.z, pX1.w};
      uint4 ph;
      cvt8(v, ph);
      *(uint4*)&Xh[rk][lb] = ph;
    }
    if (s < 17) {
      const int lo = (s + 1) * 32;
      pAH = *(const uint4*)(aHb + lo);
      pX0 = *(const float4*)(xb + lo);
      pX1 = *(const float4*)(xb + lo + 4);
    }
    __syncthreads();  // staged
    const int ar = wv * 16 + (lane & 15);
    const int ab = (lane >> 4) * 8;
    bf16x8 Ah = *(const bf16x8*)&AH[ar][ab];
#pragma unroll
    for (int dt = 0; dt < 4; ++dt) {
      const int br = dt * 16 + (lane & 15);
      bf16x8 Bh = *(const bf16x8*)&Xh[br][ab];
      acc[dt] = __builtin_amdgcn_mfma_f32_16x16x32_bf16(Ah, Bh, acc[dt], 0, 0, 0);
    }
  }

  // store raw out using PROBED positions
  float* ob = out + ((size_t)n * 64 + wv * 16) * DD + d0;
#pragma unroll
  for (int dt = 0; dt < 4; ++dt)
#pragma unroll
    for (int r = 0; r < 4; ++r)
      ob[(size_t)rowz[r] * DD + dt * 16 + colz[r]] = acc[dt][r];

  // fused per-(k, d-tile) sumsq partial (deterministic, no atomics)
#pragma unroll
  for (int r = 0; r < 4; ++r) {
    float s = 0.f;
#pragma unroll
    for (int dt = 0; dt < 4; ++dt) s = fmaf(acc[dt][r], acc[dt][r], s);
    s += __shfl_xor(s, 1, 64);
    s += __shfl_xor(s, 2, 64);
    s += __shfl_xor(s, 4, 64);
    s += __shfl_xor(s, 8, 64);
    if ((lane & 15) == 0)
      part[(size_t)b * 64 + wv * 16 + rowz[r]] = s;
  }
}

// ---------------------------------------------------------------------------
// kC3f: one block per (n,k) row. Lanes 0-11 read the 12 d-tile partials,
// shuffle-reduce, broadcast; scale row in place. ginv = 1/8 folded.
// ---------------------------------------------------------------------------
__global__ __launch_bounds__(64) void kC3f(const float* __restrict__ part,
                                           float* __restrict__ out) {
  const int row = blockIdx.x;  // n*64 + k
  const int n = row >> 6, k = row & 63;
  const int t = threadIdx.x;
  float p = (t < 12) ? part[(size_t)(n * 12 + t) * 64 + k] : 0.f;
  p += __shfl_xor(p, 1, 64);
  p += __shfl_xor(p, 2, 64);
  p += __shfl_xor(p, 4, 64);
  p += __shfl_xor(p, 8, 64);
  const float ss = __shfl(p, 0, 64);
  const float sc = 0.125f / fmaxf(sqrtf(ss), EPSF);
  float4* o = (float4*)(out + (size_t)row * DD);
#pragma unroll
  for (int j = 0; j < 3; ++j) {
    float4 v = o[t + 64 * j];
    v.x *= sc; v.y *= sc; v.z *= sc; v.w *= sc;
    o[t + 64 * j] = v;
  }
}

// ---------------------------------------------------------------------------
extern "C" void kernel_launch(void* const* d_in, const int* in_sizes, int n_in,
                              void* d_out, int out_size, void* d_ws, size_t ws_size,
                              hipStream_t stream) {
  const float* x = (const float*)d_in[0];  // [64,768,24,24]
  const float* w = (const float*)d_in[1];  // [64,768]
  float* out = (float*)d_out;              // [64, 64*768]

  u16* attH = (u16*)d_ws;                    // [64,64,576] bf16 hi only
  u16* wfH = attH + (size_t)2359296;         // W fragments hi [4*24*64*8]
  float* part = (float*)(wfH + 49152);       // [768][64] sumsq partials

  kW<<<24, 256, 0, stream>>>(w, wfH);
  kA<<<1152, 256, 0, stream>>>(x, wfH, attH);
  kB<<<768, 256, 0, stream>>>(x, attH, out, part);
  kC3f<<<4096, 64, 0, stream>>>(part, out);
}